// Round 7
// baseline (105.138 us; speedup 1.0000x reference)
//
#include <hip/hip_runtime.h>
#include <math.h>

constexpr int C = 512;
constexpr int H = 50;
constexpr int W = 75;
constexpr int NROI = 512;
constexpr int PLANE = H * W;        // 3750
constexpr int PPAD  = 3840;         // padded plane; px 3750..3839 zeroed (OOB corners, weight 0)
constexpr int NG = C / 4;           // 128 channel groups of 4
constexpr int RSPLIT = 16;
constexpr int RPB = NROI / RSPLIT;  // 32 ROIs per block
constexpr float INV_STRIDE = 1.0f / 16.0f;

typedef _Float16 h2 __attribute__((ext_vector_type(2)));
struct alignas(8) px4 { h2 a, b; }; // one pixel, 4 packed fp16 channels (8 B, 8-aligned -> ds_read2_b64)

// ---------------------------------------------------------------------------
// Prepass: bottom [C][3750] f32 -> P [128][3840] px4 (4 consecutive channels
// interleaved per pixel, fp16). Pad pixels zeroed so zero-weight OOB corners
// read harmless values.
// ---------------------------------------------------------------------------
__global__ __launch_bounds__(256) void pack_kernel(const float* __restrict__ bottom,
                                                   px4* __restrict__ P)
{
    int g = blockIdx.x;
    const float* s0 = bottom + (4 * g + 0) * PLANE;
    const float* s1 = bottom + (4 * g + 1) * PLANE;
    const float* s2 = bottom + (4 * g + 2) * PLANE;
    const float* s3 = bottom + (4 * g + 3) * PLANE;
    px4* dst = P + g * PPAD;
    for (int i = threadIdx.x; i < PPAD; i += 256) {
        px4 v;
        if (i < PLANE) {
            v.a = (h2){(_Float16)s0[i], (_Float16)s1[i]};
            v.b = (h2){(_Float16)s2[i], (_Float16)s3[i]};
        } else {
            v.a = (h2){(_Float16)0.0f, (_Float16)0.0f};
            v.b = v.a;
        }
        dst[i] = v;
    }
}

// ---------------------------------------------------------------------------
// Main: block = (4-ch group g, 32-ROI chunk); 2048 blocks, 4 blocks/CU
// (37.9 KB LDS), 2 clean rounds. Thread = (rl = t>>3, slot = t&7); iterates
// s49 = slot + 8k, so each rl-group's stores are contiguous 8-float runs and
// there is no integer division by 49. All gathers hit LDS (plane staged
// once per block); descs built in-block, read as ds_read_b64.
// __launch_bounds__(256,4): we only need 4 waves/SIMD, so give the register
// allocator up to 128 VGPRs to batch the 8 gathers per quad.
// ---------------------------------------------------------------------------
__global__ __launch_bounds__(256, 4) void roialign_main(const px4* __restrict__ P,
                                                        const float* __restrict__ rois,
                                                        float* __restrict__ out)
{
    __shared__ px4  plane[PPAD];        // 30720 B
    __shared__ uint2 xlds[RPB * 14];    // 3584 B
    __shared__ uint2 ylds[RPB * 14];    // 3584 B

    int g = blockIdx.x;
    int rbase = blockIdx.y * RPB;
    int t = threadIdx.x;

    // stage packed plane (coalesced dwordx2)
    const px4* src = P + g * PPAD;
    for (int i = t; i < PPAD; i += 256)
        plane[i] = src[i];

    // per-ROI descriptors straight into LDS (same math as all passing rounds)
    for (int e = t; e < RPB * 28; e += 256) {
        int rl = e / 28;
        int tt = e - rl * 28;
        bool isx = tt < 14;
        int j = isx ? tt : tt - 14;
        const float* r = rois + (rbase + rl) * 5;
        float lo = (isx ? r[1] : r[2]) * INV_STRIDE;
        float hi = (isx ? r[3] : r[4]) * INV_STRIDE;
        float cc = 0.5f * (lo + hi), dd = 0.5f * (hi - lo);
        float b = -1.0f + (2.0f / 13.0f) * (float)j;
        float x  = fmaf(dd, b, cc);
        float xf = floorf(x);
        int ix = (int)xf;
        float f = x - xf;
        int lim = isx ? (W - 1) : (H - 1);
        bool v0 = (ix >= 0) && (ix <= lim);
        bool v1 = (ix + 1 >= 0) && (ix + 1 <= lim);
        int off = min(max(ix, 0), lim) * (isx ? 1 : W);
        float w0 = v0 ? (1.0f - f) : 0.0f;
        float w1 = v1 ? f : 0.0f;
        h2 wh = (h2){(_Float16)w0, (_Float16)w1};
        uint2 d;
        d.x = (unsigned)off;
        d.y = __builtin_bit_cast(unsigned, wh);
        (isx ? xlds : ylds)[rl * 14 + j] = d;
    }
    __syncthreads();

    int slot = t & 7;
    int rl   = t >> 3;                  // 0..31
    const uint2* xd = xlds + rl * 14;
    const uint2* yd = ylds + rl * 14;
    float* ob = out + (size_t)((rbase + rl) * C + 4 * g) * 49;

    for (int k = 0; k < 7; ++k) {
        int s49 = slot + 8 * k;
        if (s49 > 48) break;            // only k==6, slots 1..7
        int ph = s49 / 7;               // compile-time magic-mul
        int pw = s49 - 7 * ph;

        uint2 x0 = xd[2 * pw];
        uint2 x1 = xd[2 * pw + 1];
        uint2 y0 = yd[2 * ph];
        uint2 y1 = yd[2 * ph + 1];

        h2 wx0 = __builtin_bit_cast(h2, x0.y);
        h2 wx1 = __builtin_bit_cast(h2, x1.y);
        h2 wy0 = __builtin_bit_cast(h2, y0.y);
        h2 wy1 = __builtin_bit_cast(h2, y1.y);

        h2 acca = (h2){(_Float16)(-65504.0f), (_Float16)(-65504.0f)};
        h2 accb = acca;

        auto sample = [&](int yoff, int xoff, h2 wx, h2 wy) {
            const px4* p = plane + yoff + xoff;
            px4 p00 = p[0];
            px4 p01 = p[1];             // x+1 : same ds_read2_b64 pair
            px4 p10 = p[W];
            px4 p11 = p[W + 1];
            h2 wxl = __builtin_shufflevector(wx, wx, 0, 0);
            h2 wxh = __builtin_shufflevector(wx, wx, 1, 1);
            h2 wyl = __builtin_shufflevector(wy, wy, 0, 0);
            h2 wyh = __builtin_shufflevector(wy, wy, 1, 1);
            h2 r0a = wxl * p00.a + wxh * p01.a;
            h2 r0b = wxl * p00.b + wxh * p01.b;
            h2 r1a = wxl * p10.a + wxh * p11.a;
            h2 r1b = wxl * p10.b + wxh * p11.b;
            acca = __builtin_elementwise_max(acca, wyl * r0a + wyh * r1a);
            accb = __builtin_elementwise_max(accb, wyl * r0b + wyh * r1b);
        };

        sample((int)y0.x, (int)x0.x, wx0, wy0);
        sample((int)y0.x, (int)x1.x, wx1, wy0);
        sample((int)y1.x, (int)x0.x, wx0, wy1);
        sample((int)y1.x, (int)x1.x, wx1, wy1);

        ob[s49]       = (float)acca.x;
        ob[s49 + 49]  = (float)acca.y;
        ob[s49 + 98]  = (float)accb.x;
        ob[s49 + 147] = (float)accb.y;
    }
}

extern "C" void kernel_launch(void* const* d_in, const int* in_sizes, int n_in,
                              void* d_out, int out_size, void* d_ws, size_t ws_size,
                              hipStream_t stream) {
    const float* bottom = (const float*)d_in[0];
    const float* rois   = (const float*)d_in[1];
    float* out = (float*)d_out;

    px4* P = (px4*)d_ws;   // 128 * 3840 * 8 B = 3.93 MB

    pack_kernel<<<NG, 256, 0, stream>>>(bottom, P);

    dim3 grid(NG, RSPLIT); // 128 x 16 = 2048 blocks
    roialign_main<<<grid, 256, 0, stream>>>(P, rois, out);
}

// Round 8
// 91.021 us; speedup vs baseline: 1.1551x; 1.1551x over previous
//
#include <hip/hip_runtime.h>
#include <math.h>

constexpr int C = 512;
constexpr int H = 50;
constexpr int W = 75;
constexpr int NROI = 512;
constexpr int PLANE = H * W;        // 3750
constexpr int PPAD  = 3840;         // padded plane; px 3750..3839 zeroed (OOB corners, weight 0)
constexpr int NG = C / 4;           // 128 channel groups of 4
constexpr int RSPLIT = 16;
constexpr int RPB = NROI / RSPLIT;  // 32 ROIs per block
constexpr int THREADS = 512;
constexpr float INV_STRIDE = 1.0f / 16.0f;

typedef _Float16 h2 __attribute__((ext_vector_type(2)));
struct alignas(8) px4 { h2 a, b; }; // one pixel, 4 packed fp16 channels (8 B)

// ---------------------------------------------------------------------------
// Prepass: bottom [C][3750] f32 -> P [128][3840] px4 (4 consecutive channels
// interleaved per pixel, fp16). Pad pixels zeroed. Split over 256 blocks.
// ---------------------------------------------------------------------------
__global__ __launch_bounds__(256) void pack_kernel(const float* __restrict__ bottom,
                                                   px4* __restrict__ P)
{
    int g    = blockIdx.x >> 1;
    int half = blockIdx.x & 1;
    const float* s0 = bottom + (4 * g + 0) * PLANE;
    const float* s1 = bottom + (4 * g + 1) * PLANE;
    const float* s2 = bottom + (4 * g + 2) * PLANE;
    const float* s3 = bottom + (4 * g + 3) * PLANE;
    px4* dst = P + g * PPAD;
    for (int i = half * (PPAD / 2) + threadIdx.x; i < (half + 1) * (PPAD / 2); i += 256) {
        px4 v;
        if (i < PLANE) {
            v.a = (h2){(_Float16)s0[i], (_Float16)s1[i]};
            v.b = (h2){(_Float16)s2[i], (_Float16)s3[i]};
        } else {
            v.a = (h2){(_Float16)0.0f, (_Float16)0.0f};
            v.b = v.a;
        }
        dst[i] = v;
    }
}

// ---------------------------------------------------------------------------
// Main: block = (4-ch group g, 32-ROI chunk); 2048 blocks x 512 threads.
// LDS 37.9 KB -> 4 blocks/CU -> 32 waves/CU (8/SIMD, the cap): 2x the
// latency hiding of the 256-thread variant, which measurement shows was
// stall-bound, not pipe-bound. Two 2-sample phases keep <=64 VGPR (forced
// by __launch_bounds__(512,8)) with 4 ds_read2_b64 in flight per phase.
// Descs are read as single b128 (x-pair / y-pair adjacent, 16-B aligned).
// ---------------------------------------------------------------------------
__global__ __launch_bounds__(THREADS, 8) void roialign_main(const px4* __restrict__ P,
                                                            const float* __restrict__ rois,
                                                            float* __restrict__ out)
{
    __shared__ px4  plane[PPAD];         // 30720 B
    __shared__ uint4 xlds[RPB * 7];      // [rl][pw] = {off0, w0(h2), off1, w1(h2)}  3584 B
    __shared__ uint4 ylds[RPB * 7];      // [rl][ph] = {roff0, w0,   roff1, w1}      3584 B

    int g = blockIdx.x;
    int rbase = blockIdx.y * RPB;
    int t = threadIdx.x;

    // stage packed plane, 16 B per thread-iteration (b128 both sides)
    {
        const uint4* src4 = (const uint4*)(P + g * PPAD);
        uint4* dst4 = (uint4*)plane;
        for (int i = t; i < PPAD / 2; i += THREADS)
            dst4[i] = src4[i];
    }

    // per-ROI descriptors straight into LDS (same math as all passing rounds)
    {
        uint2* xl2 = (uint2*)xlds;
        uint2* yl2 = (uint2*)ylds;
        for (int e = t; e < RPB * 28; e += THREADS) {
            int rl = e / 28;
            int tt = e - rl * 28;
            bool isx = tt < 14;
            int j = isx ? tt : tt - 14;
            const float* r = rois + (rbase + rl) * 5;
            float lo = (isx ? r[1] : r[2]) * INV_STRIDE;
            float hi = (isx ? r[3] : r[4]) * INV_STRIDE;
            float cc = 0.5f * (lo + hi), dd = 0.5f * (hi - lo);
            float b = -1.0f + (2.0f / 13.0f) * (float)j;
            float x  = fmaf(dd, b, cc);
            float xf = floorf(x);
            int ix = (int)xf;
            float f = x - xf;
            int lim = isx ? (W - 1) : (H - 1);
            bool v0 = (ix >= 0) && (ix <= lim);
            bool v1 = (ix + 1 >= 0) && (ix + 1 <= lim);
            int off = min(max(ix, 0), lim) * (isx ? 1 : W);
            float w0 = v0 ? (1.0f - f) : 0.0f;
            float w1 = v1 ? f : 0.0f;
            // splat each weight across both halves so v_pk ops need no select
            h2 wh0 = (h2){(_Float16)w0, (_Float16)w0};
            h2 wh1 = (h2){(_Float16)w1, (_Float16)w1};
            uint2 d;
            d.x = (unsigned)off;            // even dword of the uint4 pair
            d.y = __builtin_bit_cast(unsigned, wh0);
            // layout as uint4 {off_e, w_e, off_o, w_o}: entry j=2m -> first half,
            // j=2m+1 -> second half; but we must swap w-pack: store {off, w}
            (isx ? xl2 : yl2)[rl * 14 + j] = d;
            // overwrite w slot with w1 for odd? No: desc j carries (off_j, w0_j, w1_j).
            // We need both weights; pack w0,w1 into ONE dword instead:
            h2 wboth = (h2){(_Float16)w0, (_Float16)w1};
            d.y = __builtin_bit_cast(unsigned, wboth);
            (isx ? xl2 : yl2)[rl * 14 + j] = d;
        }
    }
    __syncthreads();

    for (int s = t; s < RPB * 49; s += THREADS) {
        int rl  = s / 49;
        int s49 = s - rl * 49;
        int ph  = s49 / 7;
        int pw  = s49 - ph * 7;

        uint4 xd = xlds[rl * 7 + pw];   // {offL, wLs, offR, wRs}  (w = (w0,w1) packed)
        uint4 yd = ylds[rl * 7 + ph];

        h2 wxL = __builtin_bit_cast(h2, xd.y);
        h2 wxR = __builtin_bit_cast(h2, xd.w);
        h2 wyT = __builtin_bit_cast(h2, yd.y);
        h2 wyB = __builtin_bit_cast(h2, yd.w);

        h2 acca = (h2){(_Float16)(-65504.0f), (_Float16)(-65504.0f)};
        h2 accb = acca;

        // one bilinear sample: corners at p[0],p[1],p[W],p[W+1]
        auto sample = [&](int pix, h2 wx, h2 wy) {
            const px4* p = plane + pix;
            px4 p00 = p[0];
            px4 p01 = p[1];
            px4 p10 = p[W];
            px4 p11 = p[W + 1];
            h2 wx0 = __builtin_shufflevector(wx, wx, 0, 0);
            h2 wx1 = __builtin_shufflevector(wx, wx, 1, 1);
            h2 wy0 = __builtin_shufflevector(wy, wy, 0, 0);
            h2 wy1 = __builtin_shufflevector(wy, wy, 1, 1);
            h2 r0a = wx0 * p00.a + wx1 * p01.a;
            h2 r0b = wx0 * p00.b + wx1 * p01.b;
            h2 r1a = wx0 * p10.a + wx1 * p11.a;
            h2 r1b = wx0 * p10.b + wx1 * p11.b;
            acca = __builtin_elementwise_max(acca, wy0 * r0a + wy1 * r1a);
            accb = __builtin_elementwise_max(accb, wy0 * r0b + wy1 * r1b);
        };

        // phase A: top row-pair (two x-samples)
        sample((int)yd.x + (int)xd.x, wxL, wyT);
        sample((int)yd.x + (int)xd.z, wxR, wyT);
        // phase B: bottom row-pair
        sample((int)yd.z + (int)xd.x, wxL, wyB);
        sample((int)yd.z + (int)xd.z, wxR, wyB);

        float* ob = out + (size_t)((rbase + rl) * C + 4 * g) * 49 + s49;
        ob[0]   = (float)acca.x;
        ob[49]  = (float)acca.y;
        ob[98]  = (float)accb.x;
        ob[147] = (float)accb.y;
    }
}

extern "C" void kernel_launch(void* const* d_in, const int* in_sizes, int n_in,
                              void* d_out, int out_size, void* d_ws, size_t ws_size,
                              hipStream_t stream) {
    const float* bottom = (const float*)d_in[0];
    const float* rois   = (const float*)d_in[1];
    float* out = (float*)d_out;

    px4* P = (px4*)d_ws;   // 128 * 3840 * 8 B = 3.93 MB

    pack_kernel<<<NG * 2, 256, 0, stream>>>(bottom, P);

    dim3 grid(NG, RSPLIT); // 128 x 16 = 2048 blocks
    roialign_main<<<grid, THREADS, 0, stream>>>(P, rois, out);
}

// Round 9
// 89.570 us; speedup vs baseline: 1.1738x; 1.0162x over previous
//
#include <hip/hip_runtime.h>
#include <math.h>

constexpr int C = 512;
constexpr int H = 50;
constexpr int W = 75;
constexpr int NROI = 512;
constexpr int PLANE = H * W;        // 3750
constexpr int PPAD  = 3840;         // padded plane; px 3750..3839 zeroed (OOB corners, weight 0)
constexpr int NG = C / 4;           // 128 channel groups of 4
constexpr int RSPLIT = 16;
constexpr int RPB = NROI / RSPLIT;  // 32 ROIs per block
constexpr int THREADS = 512;
constexpr float INV_STRIDE = 1.0f / 16.0f;

typedef _Float16 h2 __attribute__((ext_vector_type(2)));
struct alignas(8) px4 { h2 a, b; }; // one pixel, 4 packed fp16 channels (8 B)

// ---------------------------------------------------------------------------
// Single fused kernel: block = (4-ch group g, 32-ROI chunk), 2048 blocks x
// 512 threads, 37.9 KB LDS -> 4 blocks/CU -> 32 waves/CU (8/SIMD cap).
//
// Staging is fused (f32 bottom -> f16 px4 straight into LDS): no prepass
// kernel, no 3.9 MB global round-trip, no serialization between pack and
// gather work. Inner loop issues ALL 8 ds_read2_b64 gathers of an output
// quad before any math (~32 VGPR of load results in flight) to double
// memory-level parallelism vs the 2-phase R8 version; LDS random-gather
// bank throughput is the modeled floor.
// ---------------------------------------------------------------------------
__global__ __launch_bounds__(THREADS, 8) void roialign_fused(const float* __restrict__ bottom,
                                                             const float* __restrict__ rois,
                                                             float* __restrict__ out)
{
    __shared__ px4  plane[PPAD];         // 30720 B
    __shared__ uint4 xlds[RPB * 7];      // [rl][pw] = {offL, wL(h2 w0,w1), offR, wR}  3584 B
    __shared__ uint4 ylds[RPB * 7];      // [rl][ph] = {roffT, wT,          roffB, wB} 3584 B

    int g = blockIdx.x;
    int rbase = blockIdx.y * RPB;
    int t = threadIdx.x;

    // ---- fused staging: convert this block's 4 channels f32 -> px4 in LDS ----
    {
        const float* s0 = bottom + (4 * g + 0) * PLANE;
        const float* s1 = bottom + (4 * g + 1) * PLANE;
        const float* s2 = bottom + (4 * g + 2) * PLANE;
        const float* s3 = bottom + (4 * g + 3) * PLANE;
        for (int i = t; i < PPAD; i += THREADS) {
            px4 v;
            if (i < PLANE) {
                v.a = (h2){(_Float16)s0[i], (_Float16)s1[i]};
                v.b = (h2){(_Float16)s2[i], (_Float16)s3[i]};
            } else {
                v.a = (h2){(_Float16)0.0f, (_Float16)0.0f};
                v.b = v.a;
            }
            plane[i] = v;
        }
    }

    // ---- per-ROI interpolation descriptors (same math as all passing rounds) ----
    {
        uint2* xl2 = (uint2*)xlds;
        uint2* yl2 = (uint2*)ylds;
        for (int e = t; e < RPB * 28; e += THREADS) {
            int rl = e / 28;
            int tt = e - rl * 28;
            bool isx = tt < 14;
            int j = isx ? tt : tt - 14;
            const float* r = rois + (rbase + rl) * 5;
            float lo = (isx ? r[1] : r[2]) * INV_STRIDE;
            float hi = (isx ? r[3] : r[4]) * INV_STRIDE;
            float cc = 0.5f * (lo + hi), dd = 0.5f * (hi - lo);
            float b = -1.0f + (2.0f / 13.0f) * (float)j;
            float x  = fmaf(dd, b, cc);
            float xf = floorf(x);
            int ix = (int)xf;
            float f = x - xf;
            int lim = isx ? (W - 1) : (H - 1);
            bool v0 = (ix >= 0) && (ix <= lim);
            bool v1 = (ix + 1 >= 0) && (ix + 1 <= lim);
            int off = min(max(ix, 0), lim) * (isx ? 1 : W);
            float w0 = v0 ? (1.0f - f) : 0.0f;
            float w1 = v1 ? f : 0.0f;
            h2 wboth = (h2){(_Float16)w0, (_Float16)w1};
            uint2 d;
            d.x = (unsigned)off;
            d.y = __builtin_bit_cast(unsigned, wboth);
            (isx ? xl2 : yl2)[rl * 14 + j] = d;
        }
    }
    __syncthreads();

    // ---- gather + bilinear + maxpool ----
    auto do_quad = [&](int s) {
        int rl  = s / 49;               // magic-mul
        int s49 = s - rl * 49;
        int ph  = s49 / 7;
        int pw  = s49 - ph * 7;

        uint4 xd = xlds[rl * 7 + pw];   // {offL, wL, offR, wR}
        uint4 yd = ylds[rl * 7 + ph];   // {roffT, wT, roffB, wB}

        // issue ALL 8 gathers first (4 samples x 2 ds_read2_b64)
        const px4* pTL = plane + (int)yd.x + (int)xd.x;
        const px4* pTR = plane + (int)yd.x + (int)xd.z;
        const px4* pBL = plane + (int)yd.z + (int)xd.x;
        const px4* pBR = plane + (int)yd.z + (int)xd.z;
        px4 tl0 = pTL[0], tl1 = pTL[1], tl2 = pTL[W], tl3 = pTL[W + 1];
        px4 tr0 = pTR[0], tr1 = pTR[1], tr2 = pTR[W], tr3 = pTR[W + 1];
        px4 bl0 = pBL[0], bl1 = pBL[1], bl2 = pBL[W], bl3 = pBL[W + 1];
        px4 br0 = pBR[0], br1 = pBR[1], br2 = pBR[W], br3 = pBR[W + 1];

        h2 wxL = __builtin_bit_cast(h2, xd.y);
        h2 wxR = __builtin_bit_cast(h2, xd.w);
        h2 wyT = __builtin_bit_cast(h2, yd.y);
        h2 wyB = __builtin_bit_cast(h2, yd.w);

        auto lerp2 = [](px4 q0, px4 q1, px4 q2, px4 q3, h2 wx, h2 wy) -> px4 {
            h2 wx0 = __builtin_shufflevector(wx, wx, 0, 0);
            h2 wx1 = __builtin_shufflevector(wx, wx, 1, 1);
            h2 wy0 = __builtin_shufflevector(wy, wy, 0, 0);
            h2 wy1 = __builtin_shufflevector(wy, wy, 1, 1);
            px4 v;
            v.a = wy0 * (wx0 * q0.a + wx1 * q1.a) + wy1 * (wx0 * q2.a + wx1 * q3.a);
            v.b = wy0 * (wx0 * q0.b + wx1 * q1.b) + wy1 * (wx0 * q2.b + wx1 * q3.b);
            return v;
        };

        px4 vTL = lerp2(tl0, tl1, tl2, tl3, wxL, wyT);
        px4 vTR = lerp2(tr0, tr1, tr2, tr3, wxR, wyT);
        px4 vBL = lerp2(bl0, bl1, bl2, bl3, wxL, wyB);
        px4 vBR = lerp2(br0, br1, br2, br3, wxR, wyB);

        h2 ma = __builtin_elementwise_max(__builtin_elementwise_max(vTL.a, vTR.a),
                                          __builtin_elementwise_max(vBL.a, vBR.a));
        h2 mb = __builtin_elementwise_max(__builtin_elementwise_max(vTL.b, vTR.b),
                                          __builtin_elementwise_max(vBL.b, vBR.b));

        float* ob = out + (size_t)((rbase + rl) * C + 4 * g) * 49 + s49;
        ob[0]   = (float)ma.x;
        ob[49]  = (float)ma.y;
        ob[98]  = (float)mb.x;
        ob[147] = (float)mb.y;
    };

    // 1568 quads over 512 threads: 3 full rounds + tail for t<32
    do_quad(t);
    do_quad(t + 512);
    do_quad(t + 1024);
    if (t < 32) do_quad(t + 1536);
}

extern "C" void kernel_launch(void* const* d_in, const int* in_sizes, int n_in,
                              void* d_out, int out_size, void* d_ws, size_t ws_size,
                              hipStream_t stream) {
    const float* bottom = (const float*)d_in[0];
    const float* rois   = (const float*)d_in[1];
    float* out = (float*)d_out;

    dim3 grid(NG, RSPLIT); // 128 x 16 = 2048 blocks
    roialign_fused<<<grid, THREADS, 0, stream>>>(bottom, rois, out);
}